// Round 15
// baseline (108.142 us; speedup 1.0000x reference)
//
#include <hip/hip_runtime.h>

// INP=4096 MSK=64 HID=64 OUT=10  L1=64 L2=256 L3=128  B=16384  WVEC=4810
// SINGLE fused kernel (grid 256 x 512, 1 block/CU by LDS):
//   idx -> wave 7 issues ALL xm random gathers (outstanding across raw
//   barriers) -> waves 0-6 do PREP under the gather (W1 transpose tiled in
//   dead LDS for blocks 0-63; W4 fragment-order + W2/W3 f16 for blocks
//   64-255) -> software GRID BARRIER (threadfence + device atomicAdd +
//   spin; gather loads stay in flight) -> front L1 dedup / L2 / L3 f16
//   MFMA -> gather drain -> register-resident W4 GEMM + fused epilogues.
// Prep outputs are replay-invariant => cross-XCD stale-L2 is benign; the
// barrier guarantees replay-1 correctness. sync counter zeroed per call
// via hipMemsetAsync (graph-capturable).

typedef _Float16 f16;
typedef _Float16 f16x8 __attribute__((ext_vector_type(8)));
typedef _Float16 f16x4 __attribute__((ext_vector_type(4)));
typedef float    f32x4 __attribute__((ext_vector_type(4)));

#define NPAD 4864   // 4810 W4 rows padded to 76*64

#define BAR() do { asm volatile("s_waitcnt lgkmcnt(0)" ::: "memory"); \
                   __builtin_amdgcn_s_barrier();                      \
                   asm volatile("" ::: "memory"); } while (0)

// ---------------------------------------------------------------- all-in-one
__global__ __launch_bounds__(512, 2) void k_all(
    const float* __restrict__ data, const int* __restrict__ midx,
    const float* __restrict__ W1, const float* __restrict__ b1,
    const float* __restrict__ W2, const float* __restrict__ b2,
    const float* __restrict__ W3, const float* __restrict__ b3,
    const float* __restrict__ W4, const float* __restrict__ b4,
    f16* __restrict__ W1Th, f16* __restrict__ W2h,
    f16* __restrict__ W3h, f16* __restrict__ W4s,
    int* __restrict__ sync_cnt,
    float* __restrict__ out)
{
    __shared__ __align__(16) int   idx_s[64 * 64];    // 16 KB
    __shared__ __align__(16) char  h1b[8192];         // h1 f16 swz
    __shared__ __align__(16) char  h2b[32768];        // h2 swz / prep tile
    __shared__ __align__(16) char  h3b[16384];        // h3 f16 swz
    __shared__ __align__(16) float xm_s[64 * 68];
    __shared__ __align__(16) float hid_s[64 * 68];
    __shared__ __align__(16) f16   w64_s[64 * 64];
    __shared__ __align__(16) float res_s[64 * 12];
    __shared__ __align__(16) float res_b[64 * 12];

    const int t = threadIdx.x, w = t >> 6, lane = t & 63;
    const int lr = lane & 15, g = lane >> 4;
    const int bid = blockIdx.x;
    const int row0 = bid * 64;
    const f32x4 zero = {0.f, 0.f, 0.f, 0.f};

    // ---- stage idx (all waves; these loads retire before wave-7 gathers)
    for (int e = t; e < 4096; e += 512)
        idx_s[e] = midx[(size_t)row0 * 64 + e];
    BAR();                                   // B0: idx ready

    float xr[64];                            // live only on wave-7 path

    // ---- [wave 7: issue ALL gathers] [waves 0-6: prep part A]
    if (w == 7) {
        #pragma unroll
        for (int k = 0; k < 64; ++k)
            xr[k] = data[(size_t)(row0 + k) * 4096 + idx_s[k * 64 + lane]];
        __builtin_amdgcn_sched_barrier(0);
    } else {
        if (bid < 64) {
            // W1[64][4096] -> tile (aliases h2b; h2 unused until L2 phase)
            if (w < 4) {
                float* tile = (float*)h2b;           // [64][65]
                const int r4 = t >> 6, c0 = t & 63;
                #pragma unroll
                for (int rr = 0; rr < 16; ++rr) {
                    const int i = rr * 4 + r4;
                    tile[i * 65 + c0] = W1[(size_t)i * 4096 + bid * 64 + c0];
                }
            }
        } else {
            // W4 fragment-order + W2/W3 f16, sliced over blocks 64-255
            const int tid = (bid - 64) * 384 + t;    // t < 384 here (w<7 -> t<448; waves 6 idle-safe below)
            const int stride = 192 * 384;
            if (t < 384) {
                for (int e = tid; e < NPAD * 128; e += stride) {
                    const int j    = e & 7;
                    const int ln   = (e >> 3) & 63;
                    const int mt   = (e >> 9) & 3;
                    const int kk   = (e >> 11) & 3;
                    const int c    = e >> 13;
                    const int lrr = ln & 15, gg = ln >> 4;
                    const int row = 64 * c + 16 * mt + lrr;
                    const int col = 32 * kk + 8 * gg + j;
                    W4s[e] = (row < 4810) ? (f16)W4[(size_t)row * 128 + col] : (f16)0.f;
                }
                for (int e = tid; e < 256 * 64; e += stride)  W2h[e] = (f16)W2[e];
                for (int e = tid; e < 128 * 256; e += stride) W3h[e] = (f16)W3[e];
            }
        }
    }
    BAR();                                   // B1: tile loaded / slices done

    // ---- prep part B: transpose write-out (blocks < 64)
    if (w < 7 && bid < 64 && w < 4) {
        const float* tile = (const float*)h2b;
        const int r4 = t >> 6, c0 = t & 63;
        #pragma unroll
        for (int rr = 0; rr < 16; ++rr) {
            const int jj = rr * 4 + r4;
            W1Th[(size_t)(bid * 64 + jj) * 64 + c0] = (f16)tile[c0 * 65 + jj];
        }
    }
    // drain prep stores (waves 0-6 only; wave 7 keeps gathers outstanding)
    if (w < 7) asm volatile("s_waitcnt vmcnt(0)" ::: "memory");
    BAR();                                   // B2: local prep complete

    // ---- software grid barrier (thread 0 only; device-scope)
    if (t == 0) {
        __threadfence();
        atomicAdd(sync_cnt, 1);
        while (__hip_atomic_load(sync_cnt, __ATOMIC_ACQUIRE,
                                 __HIP_MEMORY_SCOPE_AGENT) < 256)
            __builtin_amdgcn_s_sleep(2);
        __threadfence();
    }
    BAR();                                   // B3: all prep globally visible

    // ---- L1 dedup gather-sum (waves 0-6): sample-pairs sp = w, w+7, ...
    if (w < 7) {
        const f32x4 b1v = *(const f32x4*)&b1[lr * 4];
        for (int sp = w; sp < 32; sp += 7) {
            const int s0 = 2 * sp, s1 = s0 + 1;
            f32x4 a0 = zero, a1 = zero;
            #pragma unroll
            for (int tt = 0; tt < 16; ++tt) {
                const int i = g * 16 + tt;
                const int c0 = idx_s[s0 * 64 + i];
                const int q0 = (i > 0) ? idx_s[s0 * 64 + i - 1] : -1;
                const int c1 = idx_s[s1 * 64 + i];
                const int q1 = (i > 0) ? idx_s[s1 * 64 + i - 1] : -1;
                const f16x4 w0 = *(const f16x4*)&W1Th[c0 * 64 + lr * 4];
                const f16x4 w1 = *(const f16x4*)&W1Th[c1 * 64 + lr * 4];
                #pragma unroll
                for (int q = 0; q < 4; ++q) {
                    a0[q] += (c0 != q0) ? (float)w0[q] : 0.f;
                    a1[q] += (c1 != q1) ? (float)w1[q] : 0.f;
                }
            }
            #pragma unroll
            for (int q = 0; q < 4; ++q) {
                a0[q] += __shfl_xor(a0[q], 16);
                a0[q] += __shfl_xor(a0[q], 32);
                a1[q] += __shfl_xor(a1[q], 16);
                a1[q] += __shfl_xor(a1[q], 32);
            }
            if (g == 0) {
                f16x4 h0, h1v;
                #pragma unroll
                for (int q = 0; q < 4; ++q) {
                    h0[q]  = (f16)fmaxf(a0[q] + b1v[q], 0.f);
                    h1v[q] = (f16)fmaxf(a1[q] + b1v[q], 0.f);
                }
                *(f16x4*)(h1b + ((s0 * 128 + lr * 8) ^ ((s0 & 7) << 4))) = h0;
                *(f16x4*)(h1b + ((s1 * 128 + lr * 8) ^ ((s1 & 7) << 4))) = h1v;
            }
        }
    }
    BAR();                                   // B4: h1 ready

    if (w < 7) {
        // ---- L2: n-blocks of 32, nb = w, w+7
        f16x8 bh[4][2];
        #pragma unroll
        for (int rt = 0; rt < 4; ++rt)
            #pragma unroll
            for (int kk = 0; kk < 2; ++kk) {
                const int s = 16 * rt + lr;
                bh[rt][kk] = *(const f16x8*)(h1b + ((s * 128 + (32 * kk + 8 * g) * 2) ^ ((s & 7) << 4)));
            }
        for (int nb = w; nb < 8; nb += 7) {
            const int n0 = 32 * nb;
            f16x8 a2[2][2];
            #pragma unroll
            for (int mt = 0; mt < 2; ++mt)
                #pragma unroll
                for (int kk = 0; kk < 2; ++kk)
                    a2[mt][kk] = *(const f16x8*)&W2h[(n0 + 16 * mt + lr) * 64 + 32 * kk + 8 * g];
            f32x4 acc2[2][4];
            #pragma unroll
            for (int mt = 0; mt < 2; ++mt)
                #pragma unroll
                for (int rt = 0; rt < 4; ++rt) {
                    acc2[mt][rt] = __builtin_amdgcn_mfma_f32_16x16x32_f16(a2[mt][0], bh[rt][0], zero, 0, 0, 0);
                    acc2[mt][rt] = __builtin_amdgcn_mfma_f32_16x16x32_f16(a2[mt][1], bh[rt][1], acc2[mt][rt], 0, 0, 0);
                }
            #pragma unroll
            for (int mt = 0; mt < 2; ++mt) {
                const f32x4 bv = *(const f32x4*)&b2[n0 + 16 * mt + 4 * g];
                #pragma unroll
                for (int rt = 0; rt < 4; ++rt) {
                    const int s = 16 * rt + lr;
                    f16x4 hv;
                    #pragma unroll
                    for (int q = 0; q < 4; ++q)
                        hv[q] = (f16)fmaxf(acc2[mt][rt][q] + bv[q], 0.f);
                    *(f16x4*)(h2b + ((s * 512 + (n0 + 16 * mt + 4 * g) * 2) ^ ((s & 7) << 4))) = hv;
                }
            }
        }
    }
    BAR();                                   // B5: h2 ready

    if (w < 7) {
        // ---- L3: n-blocks of 16, nb = w, w+7
        for (int nb = w; nb < 8; nb += 7) {
            const int n0 = 16 * nb;
            f32x4 acc3[4] = {zero, zero, zero, zero};
            #pragma unroll 2
            for (int kk = 0; kk < 8; ++kk) {
                const f16x8 a3 = *(const f16x8*)&W3h[(n0 + lr) * 256 + 32 * kk + 8 * g];
                #pragma unroll
                for (int rt = 0; rt < 4; ++rt) {
                    const int s = 16 * rt + lr;
                    const f16x8 bb = *(const f16x8*)(h2b + ((s * 512 + (32 * kk + 8 * g) * 2) ^ ((s & 7) << 4)));
                    acc3[rt] = __builtin_amdgcn_mfma_f32_16x16x32_f16(a3, bb, acc3[rt], 0, 0, 0);
                }
            }
            const f32x4 bv3 = *(const f32x4*)&b3[n0 + 4 * g];
            #pragma unroll
            for (int rt = 0; rt < 4; ++rt) {
                const int s = 16 * rt + lr;
                f16x4 hv;
                #pragma unroll
                for (int q = 0; q < 4; ++q)
                    hv[q] = (f16)fmaxf(acc3[rt][q] + bv3[q], 0.f);
                *(f16x4*)(h3b + ((s * 256 + (n0 + 4 * g) * 2) ^ ((s & 7) << 4))) = hv;
            }
        }
    }
    BAR();                                   // B6: h3 ready

    // ---- all waves: B-fragments for all 64 samples
    f16x8 bfrag[4][4];                       // [kk][u]
    #pragma unroll
    for (int u = 0; u < 4; ++u)
        #pragma unroll
        for (int kk = 0; kk < 4; ++kk) {
            const int s = 16 * u + lr;
            bfrag[kk][u] = *(const f16x8*)(h3b + ((s * 256 + (32 * kk + 8 * g) * 2) ^ ((s & 7) << 4)));
        }
    if (w == 7) {
        // drain gathers (in-order vmcnt) -> xm_s
        #pragma unroll
        for (int k = 0; k < 64; ++k)
            xm_s[k * 68 + lane] = xr[k];
    }
    BAR();                                   // B7: xm ready

    // xm packed f16 registers
    f16x4 xmr[4][4];                         // [mt][u]
    #pragma unroll
    for (int mt = 0; mt < 4; ++mt)
        #pragma unroll
        for (int u = 0; u < 4; ++u) {
            const f32x4 xv = *(const f32x4*)&xm_s[(16 * u + lr) * 68 + 16 * mt + 4 * g];
            f16x4 xh;
            #pragma unroll
            for (int q = 0; q < 4; ++q) xh[q] = (f16)xv[q];
            xmr[mt][u] = xh;
        }

    const char* W4b = (const char*)W4s;
    const int afoff = lane * 16;

#define LDAF(dst, c, kk) { const char* cb_ = W4b + (size_t)(c) * 16384 + (kk) * 4096 + afoff; \
    dst[0] = *(const f16x8*)(cb_);        dst[1] = *(const f16x8*)(cb_ + 1024); \
    dst[2] = *(const f16x8*)(cb_ + 2048); dst[3] = *(const f16x8*)(cb_ + 3072); }

#define MFMA16(af, kk) { \
    _Pragma("unroll") for (int mt = 0; mt < 4; ++mt) \
    _Pragma("unroll") for (int u = 0; u < 4; ++u) \
        acc[mt][u] = __builtin_amdgcn_mfma_f32_16x16x32_f16(af[mt], bfrag[kk][u], acc[mt][u], 0, 0, 0); }

    // ---- inp chunks 0..64 (8 waves): c = w, w+8, ...
    for (int c = w; c < 65; c += 8) {
        f16x8 afA[4], afB[4];
        LDAF(afA, c, 0)
        LDAF(afB, c, 1)
        f32x4 acc[4][4];
        #pragma unroll
        for (int mt = 0; mt < 4; ++mt)
            #pragma unroll
            for (int u = 0; u < 4; ++u)
                acc[mt][u] = __builtin_amdgcn_mfma_f32_16x16x32_f16(afA[mt], bfrag[0][u], zero, 0, 0, 0);
        LDAF(afA, c, 2)
        MFMA16(afB, 1)
        LDAF(afB, c, 3)
        MFMA16(afA, 2)
        MFMA16(afB, 3)

        f32x4 bv[4];
        #pragma unroll
        for (int mt = 0; mt < 4; ++mt)
            bv[mt] = *(const f32x4*)&b4[64 * c + 16 * mt + 4 * g];

        if (c < 64) {                        // inp_w: dot with xm -> hid_s
            #pragma unroll
            for (int u = 0; u < 4; ++u) {
                float sum = 0.f;
                #pragma unroll
                for (int mt = 0; mt < 4; ++mt)
                    #pragma unroll
                    for (int q = 0; q < 4; ++q)
                        sum += (acc[mt][u][q] + bv[mt][q]) * (float)xmr[mt][u][q];
                sum += __shfl_xor(sum, 16);
                sum += __shfl_xor(sum, 32);
                if (g == 0) hid_s[(16 * u + lr) * 68 + c] = sum;
            }
        } else {                             // inp_b tile -> w64_s (f16)
            #pragma unroll
            for (int u = 0; u < 4; ++u)
                #pragma unroll
                for (int mt = 0; mt < 4; ++mt) {
                    f16x4 wv;
                    #pragma unroll
                    for (int q = 0; q < 4; ++q)
                        wv[q] = (f16)(acc[mt][u][q] + bv[mt][q]);
                    *(f16x4*)&w64_s[(16 * u + lr) * 64 + 16 * mt + 4 * g] = wv;
                }
        }
    }
    BAR();                                   // B8: hid dots + w64 done

    // ---- hid registers with fused inp_b add + ReLU
    f16x4 hidr[4][4];                        // [mt][u]
    #pragma unroll
    for (int mt = 0; mt < 4; ++mt)
        #pragma unroll
        for (int u = 0; u < 4; ++u) {
            const int s = 16 * u + lr;
            f16x4 xh;
            #pragma unroll
            for (int q = 0; q < 4; ++q) {
                const int h = 16 * mt + 4 * g + q;
                xh[q] = (f16)fmaxf(hid_s[s * 68 + h] + (float)w64_s[s * 64 + h], 0.f);
            }
            hidr[mt][u] = xh;
        }

    // ---- out chunks 65..74: wave w -> 65+w; waves 0,1 also 73,74
    auto do_out = [&](int c) {
        f32x4 bv[4];
        #pragma unroll
        for (int mt = 0; mt < 4; ++mt)
            bv[mt] = *(const f32x4*)&b4[64 * c + 16 * mt + 4 * g];
        f16x8 afA[4], afB[4];
        LDAF(afA, c, 0)
        LDAF(afB, c, 1)
        f32x4 acc[4][4];
        #pragma unroll
        for (int mt = 0; mt < 4; ++mt)
            #pragma unroll
            for (int u = 0; u < 4; ++u)
                acc[mt][u] = __builtin_amdgcn_mfma_f32_16x16x32_f16(afA[mt], bfrag[0][u], zero, 0, 0, 0);
        LDAF(afA, c, 2)
        MFMA16(afB, 1)
        LDAF(afB, c, 3)
        MFMA16(afA, 2)
        MFMA16(afB, 3)
        #pragma unroll
        for (int u = 0; u < 4; ++u) {
            float sum = 0.f;
            #pragma unroll
            for (int mt = 0; mt < 4; ++mt)
                #pragma unroll
                for (int q = 0; q < 4; ++q)
                    sum += (acc[mt][u][q] + bv[mt][q]) * (float)hidr[mt][u][q];
            sum += __shfl_xor(sum, 16);
            sum += __shfl_xor(sum, 32);
            if (g == 0) res_s[(16 * u + lr) * 12 + (c - 65)] = sum;
        }
    };
    do_out(65 + w);
    if (w < 2) do_out(73 + w);

    // ---- chunk 75 (out_b rows 4800..4809): wave 2 -> res_b
    if (w == 2) {
        f32x4 accb[4] = {zero, zero, zero, zero};
        #pragma unroll
        for (int kk = 0; kk < 4; ++kk) {
            const f16x8 af = *(const f16x8*)(W4b + (size_t)75 * 16384 + kk * 4096 + afoff);
            #pragma unroll
            for (int u = 0; u < 4; ++u)
                accb[u] = __builtin_amdgcn_mfma_f32_16x16x32_f16(af, bfrag[kk][u], accb[u], 0, 0, 0);
        }
        #pragma unroll
        for (int u = 0; u < 4; ++u)
            #pragma unroll
            for (int q = 0; q < 4; ++q) {
                const int o = 4 * g + q;
                if (o < 10)
                    res_b[(16 * u + lr) * 12 + o] = accb[u][q] + b4[4800 + o];
            }
    }
    BAR();                                   // B9: res ready

    for (int e = t; e < 640; e += 512)
        out[(size_t)row0 * 10 + e] =
            res_s[(e / 10) * 12 + (e % 10)] + res_b[(e / 10) * 12 + (e % 10)];
#undef LDAF
#undef MFMA16
}

// ---------------------------------------------------------------- launcher
extern "C" void kernel_launch(void* const* d_in, const int* in_sizes, int n_in,
                              void* d_out, int out_size, void* d_ws, size_t ws_size,
                              hipStream_t stream)
{
    const float* data = (const float*)d_in[0];
    const int*   midx = (const int*)d_in[1];
    const float* W1   = (const float*)d_in[2];
    const float* b1   = (const float*)d_in[3];
    const float* W2   = (const float*)d_in[4];
    const float* b2   = (const float*)d_in[5];
    const float* W3   = (const float*)d_in[6];
    const float* b3   = (const float*)d_in[7];
    const float* W4   = (const float*)d_in[8];
    const float* b4   = (const float*)d_in[9];
    float* out = (float*)d_out;

    f16* W1Th = (f16*)d_ws;                    // 262144 f16
    f16* W4s  = W1Th + (size_t)4096 * 64;      // 622592 f16 (fragment-ordered)
    f16* W2h  = W4s + (size_t)NPAD * 128;      // 16384 f16
    f16* W3h  = W2h + 256 * 64;                // 32768 f16
    int* sync_cnt = (int*)(W3h + 128 * 256);   // 1 int

    hipMemsetAsync(sync_cnt, 0, sizeof(int), stream);
    k_all<<<256, 512, 0, stream>>>(data, midx, W1, b1, W2, b2, W3, b3, W4, b4,
                                   W1Th, W2h, W3h, W4s, sync_cnt, out);
}

// Round 16
// 75.889 us; speedup vs baseline: 1.4250x; 1.4250x over previous
//
#include <hip/hip_runtime.h>

// INP=4096 MSK=64 HID=64 OUT=10  L1=64 L2=256 L3=128  B=16384  WVEC=4810
// k_prep : W1 LDS-tiled transpose -> f16; W2/W3 f16; W4 fragment-order f16.
// k_main : 32 samples/block, grid 512, 2 blocks/CU (~60KB LDS, <=128 VGPR).
//   r11 structure halved: wave 7 = parked gather producer (32 loads
//   outstanding across raw barriers), waves 0-6 front (L1 dedup, L2/L3
//   f16 MFMA), then all 8 waves register-resident W4 GEMM (fragment-
//   ordered A from L2, 2 u-sets) + fused epilogues. Block-level TLP:
//   while block A parks at its gather drain, block B computes.

typedef _Float16 f16;
typedef _Float16 f16x8 __attribute__((ext_vector_type(8)));
typedef _Float16 f16x4 __attribute__((ext_vector_type(4)));
typedef float    f32x4 __attribute__((ext_vector_type(4)));

#define NPAD 4864   // 4810 W4 rows padded to 76*64

#define BAR() do { asm volatile("s_waitcnt lgkmcnt(0)" ::: "memory"); \
                   __builtin_amdgcn_s_barrier();                      \
                   asm volatile("" ::: "memory"); } while (0)

// ---------------------------------------------------------------- prep
__global__ __launch_bounds__(256) void k_prep(
    const float* __restrict__ W1, const float* __restrict__ W2,
    const float* __restrict__ W3, const float* __restrict__ W4,
    f16* __restrict__ W1Th, f16* __restrict__ W2h,
    f16* __restrict__ W3h, f16* __restrict__ W4s)
{
    const int bid = blockIdx.x;
    const int t = threadIdx.x;

    if (bid < 64) {
        // ---- W1[64][4096] -> W1Th[4096][64], LDS-tiled 64x64 transpose
        __shared__ float tile[64][65];
        const int r4 = t >> 6, c0 = t & 63;
        #pragma unroll
        for (int rr = 0; rr < 16; ++rr) {
            const int i = rr * 4 + r4;
            tile[i][c0] = W1[(size_t)i * 4096 + bid * 64 + c0];
        }
        __syncthreads();
        #pragma unroll
        for (int rr = 0; rr < 16; ++rr) {
            const int jj = rr * 4 + r4;
            W1Th[(size_t)(bid * 64 + jj) * 64 + c0] = (f16)tile[c0][jj];
        }
        return;
    }

    const int tid = (bid - 64) * 256 + t;
    const int stride = (gridDim.x - 64) * 256;
    for (int e = tid; e < NPAD * 128; e += stride) {
        const int j    = e & 7;
        const int lane = (e >> 3) & 63;
        const int mt   = (e >> 9) & 3;
        const int kk   = (e >> 11) & 3;
        const int c    = e >> 13;
        const int lr = lane & 15, g = lane >> 4;
        const int row = 64 * c + 16 * mt + lr;
        const int col = 32 * kk + 8 * g + j;
        W4s[e] = (row < 4810) ? (f16)W4[(size_t)row * 128 + col] : (f16)0.f;
    }
    for (int e = tid; e < 256 * 64; e += stride)  W2h[e] = (f16)W2[e];
    for (int e = tid; e < 128 * 256; e += stride) W3h[e] = (f16)W3[e];
}

// ---------------------------------------------------------------- main
__global__ __launch_bounds__(512, 4) void k_main(
    const float* __restrict__ data, const int* __restrict__ midx,
    const f16* __restrict__ W1Th, const float* __restrict__ b1,
    const f16* __restrict__ W2h, const float* __restrict__ b2,
    const f16* __restrict__ W3h, const float* __restrict__ b3,
    const f16* __restrict__ W4s, const float* __restrict__ b4,
    float* __restrict__ out)
{
    __shared__ __align__(16) int   idx_s[32 * 64];    // 8 KB
    __shared__ __align__(16) char  h1b[4096];         // h1 f16 swz
    __shared__ __align__(16) char  h2b[16384];        // h2 f16 swz
    __shared__ __align__(16) char  h3b[8192];         // h3 f16 swz
    __shared__ __align__(16) float xm_s[32 * 68];     // 8.7 KB
    __shared__ __align__(16) float hid_s[32 * 68];    // 8.7 KB
    __shared__ __align__(16) f16   w64_s[32 * 64];    // 4 KB
    __shared__ __align__(16) float res_s[32 * 12];
    __shared__ __align__(16) float res_b[32 * 12];

    const int t = threadIdx.x, w = t >> 6, lane = t & 63;
    const int lr = lane & 15, g = lane >> 4;
    const int row0 = blockIdx.x * 32;
    const f32x4 zero = {0.f, 0.f, 0.f, 0.f};

    // ---- stage idx (all waves; retire before wave-7 gathers)
    for (int e = t; e < 2048; e += 512)
        idx_s[e] = midx[(size_t)row0 * 64 + e];
    BAR();                                   // B0: idx ready

    float xr[32];                            // live only on wave-7 path

    if (w == 7) {
        // ---- issue ALL 32 gather instrs; keep outstanding across barriers
        #pragma unroll
        for (int k = 0; k < 32; ++k)
            xr[k] = data[(size_t)(row0 + k) * 4096 + idx_s[k * 64 + lane]];
        __builtin_amdgcn_sched_barrier(0);
    } else {
        // ---- L1 dedup gather-sum: sample-pairs sp = w, w+7 (<16)
        const f32x4 b1v = *(const f32x4*)&b1[lr * 4];
        for (int sp = w; sp < 16; sp += 7) {
            const int s0 = 2 * sp, s1 = s0 + 1;
            f32x4 a0 = zero, a1 = zero;
            #pragma unroll
            for (int tt = 0; tt < 16; ++tt) {
                const int i = g * 16 + tt;
                const int c0 = idx_s[s0 * 64 + i];
                const int q0 = (i > 0) ? idx_s[s0 * 64 + i - 1] : -1;
                const int c1 = idx_s[s1 * 64 + i];
                const int q1 = (i > 0) ? idx_s[s1 * 64 + i - 1] : -1;
                const f16x4 w0 = *(const f16x4*)&W1Th[c0 * 64 + lr * 4];
                const f16x4 w1 = *(const f16x4*)&W1Th[c1 * 64 + lr * 4];
                #pragma unroll
                for (int q = 0; q < 4; ++q) {
                    a0[q] += (c0 != q0) ? (float)w0[q] : 0.f;
                    a1[q] += (c1 != q1) ? (float)w1[q] : 0.f;
                }
            }
            #pragma unroll
            for (int q = 0; q < 4; ++q) {
                a0[q] += __shfl_xor(a0[q], 16);
                a0[q] += __shfl_xor(a0[q], 32);
                a1[q] += __shfl_xor(a1[q], 16);
                a1[q] += __shfl_xor(a1[q], 32);
            }
            if (g == 0) {
                f16x4 h0, h1v;
                #pragma unroll
                for (int q = 0; q < 4; ++q) {
                    h0[q]  = (f16)fmaxf(a0[q] + b1v[q], 0.f);
                    h1v[q] = (f16)fmaxf(a1[q] + b1v[q], 0.f);
                }
                *(f16x4*)(h1b + ((s0 * 128 + lr * 8) ^ ((s0 & 7) << 4))) = h0;
                *(f16x4*)(h1b + ((s1 * 128 + lr * 8) ^ ((s1 & 7) << 4))) = h1v;
            }
        }
    }
    BAR();                                   // B1: h1 ready

    if (w < 7) {
        // ---- L2: n-blocks of 32, nb = w, w+7 (16-row B tile, rt<2)
        f16x8 bh[2][2];
        #pragma unroll
        for (int rt = 0; rt < 2; ++rt)
            #pragma unroll
            for (int kk = 0; kk < 2; ++kk) {
                const int s = 16 * rt + lr;
                bh[rt][kk] = *(const f16x8*)(h1b + ((s * 128 + (32 * kk + 8 * g) * 2) ^ ((s & 7) << 4)));
            }
        for (int nb = w; nb < 8; nb += 7) {
            const int n0 = 32 * nb;
            f16x8 a2[2][2];
            #pragma unroll
            for (int mt = 0; mt < 2; ++mt)
                #pragma unroll
                for (int kk = 0; kk < 2; ++kk)
                    a2[mt][kk] = *(const f16x8*)&W2h[(n0 + 16 * mt + lr) * 64 + 32 * kk + 8 * g];
            f32x4 acc2[2][2];
            #pragma unroll
            for (int mt = 0; mt < 2; ++mt)
                #pragma unroll
                for (int rt = 0; rt < 2; ++rt) {
                    acc2[mt][rt] = __builtin_amdgcn_mfma_f32_16x16x32_f16(a2[mt][0], bh[rt][0], zero, 0, 0, 0);
                    acc2[mt][rt] = __builtin_amdgcn_mfma_f32_16x16x32_f16(a2[mt][1], bh[rt][1], acc2[mt][rt], 0, 0, 0);
                }
            #pragma unroll
            for (int mt = 0; mt < 2; ++mt) {
                const f32x4 bv = *(const f32x4*)&b2[n0 + 16 * mt + 4 * g];
                #pragma unroll
                for (int rt = 0; rt < 2; ++rt) {
                    const int s = 16 * rt + lr;
                    f16x4 hv;
                    #pragma unroll
                    for (int q = 0; q < 4; ++q)
                        hv[q] = (f16)fmaxf(acc2[mt][rt][q] + bv[q], 0.f);
                    *(f16x4*)(h2b + ((s * 512 + (n0 + 16 * mt + 4 * g) * 2) ^ ((s & 7) << 4))) = hv;
                }
            }
        }
    }
    BAR();                                   // B2: h2 ready

    if (w < 7) {
        // ---- L3: n-blocks of 16, nb = w, w+7
        for (int nb = w; nb < 8; nb += 7) {
            const int n0 = 16 * nb;
            f32x4 acc3[2] = {zero, zero};
            #pragma unroll 2
            for (int kk = 0; kk < 8; ++kk) {
                const f16x8 a3 = *(const f16x8*)&W3h[(n0 + lr) * 256 + 32 * kk + 8 * g];
                #pragma unroll
                for (int rt = 0; rt < 2; ++rt) {
                    const int s = 16 * rt + lr;
                    const f16x8 bb = *(const f16x8*)(h2b + ((s * 512 + (32 * kk + 8 * g) * 2) ^ ((s & 7) << 4)));
                    acc3[rt] = __builtin_amdgcn_mfma_f32_16x16x32_f16(a3, bb, acc3[rt], 0, 0, 0);
                }
            }
            const f32x4 bv3 = *(const f32x4*)&b3[n0 + 4 * g];
            #pragma unroll
            for (int rt = 0; rt < 2; ++rt) {
                const int s = 16 * rt + lr;
                f16x4 hv;
                #pragma unroll
                for (int q = 0; q < 4; ++q)
                    hv[q] = (f16)fmaxf(acc3[rt][q] + bv3[q], 0.f);
                *(f16x4*)(h3b + ((s * 256 + (n0 + 4 * g) * 2) ^ ((s & 7) << 4))) = hv;
            }
        }
    }
    BAR();                                   // B3: h3 ready

    // ---- all waves: B-fragments for 32 samples (2 u-sets)
    f16x8 bfrag[4][2];                       // [kk][u]
    #pragma unroll
    for (int u = 0; u < 2; ++u)
        #pragma unroll
        for (int kk = 0; kk < 4; ++kk) {
            const int s = 16 * u + lr;
            bfrag[kk][u] = *(const f16x8*)(h3b + ((s * 256 + (32 * kk + 8 * g) * 2) ^ ((s & 7) << 4)));
        }
    if (w == 7) {
        // drain own gathers -> xm_s
        #pragma unroll
        for (int k = 0; k < 32; ++k)
            xm_s[k * 68 + lane] = xr[k];
    }
    BAR();                                   // B4: xm ready

    // xm packed f16 registers
    f16x4 xmr[4][2];                         // [mt][u]
    #pragma unroll
    for (int mt = 0; mt < 4; ++mt)
        #pragma unroll
        for (int u = 0; u < 2; ++u) {
            const f32x4 xv = *(const f32x4*)&xm_s[(16 * u + lr) * 68 + 16 * mt + 4 * g];
            f16x4 xh;
            #pragma unroll
            for (int q = 0; q < 4; ++q) xh[q] = (f16)xv[q];
            xmr[mt][u] = xh;
        }

    const char* W4b = (const char*)W4s;
    const int afoff = lane * 16;

#define LDAF(dst, c, kk) { const char* cb_ = W4b + (size_t)(c) * 16384 + (kk) * 4096 + afoff; \
    dst[0] = *(const f16x8*)(cb_);        dst[1] = *(const f16x8*)(cb_ + 1024); \
    dst[2] = *(const f16x8*)(cb_ + 2048); dst[3] = *(const f16x8*)(cb_ + 3072); }

#define MFMA8(af, kk) { \
    _Pragma("unroll") for (int mt = 0; mt < 4; ++mt) \
    _Pragma("unroll") for (int u = 0; u < 2; ++u) \
        acc[mt][u] = __builtin_amdgcn_mfma_f32_16x16x32_f16(af[mt], bfrag[kk][u], acc[mt][u], 0, 0, 0); }

    // ---- inp chunks 0..64 (8 waves): c = w, w+8, ...
    for (int c = w; c < 65; c += 8) {
        f32x4 acc[4][2];
        #pragma unroll
        for (int mt = 0; mt < 4; ++mt)
            #pragma unroll
            for (int u = 0; u < 2; ++u) acc[mt][u] = zero;
        #pragma unroll
        for (int kk = 0; kk < 4; ++kk) {
            f16x8 af[4];
            LDAF(af, c, kk)
            MFMA8(af, kk)
        }

        f32x4 bv[4];
        #pragma unroll
        for (int mt = 0; mt < 4; ++mt)
            bv[mt] = *(const f32x4*)&b4[64 * c + 16 * mt + 4 * g];

        if (c < 64) {                        // inp_w: dot with xm -> hid_s
            #pragma unroll
            for (int u = 0; u < 2; ++u) {
                float sum = 0.f;
                #pragma unroll
                for (int mt = 0; mt < 4; ++mt)
                    #pragma unroll
                    for (int q = 0; q < 4; ++q)
                        sum += (acc[mt][u][q] + bv[mt][q]) * (float)xmr[mt][u][q];
                sum += __shfl_xor(sum, 16);
                sum += __shfl_xor(sum, 32);
                if (g == 0) hid_s[(16 * u + lr) * 68 + c] = sum;
            }
        } else {                             // inp_b tile -> w64_s (f16)
            #pragma unroll
            for (int u = 0; u < 2; ++u)
                #pragma unroll
                for (int mt = 0; mt < 4; ++mt) {
                    f16x4 wv;
                    #pragma unroll
                    for (int q = 0; q < 4; ++q)
                        wv[q] = (f16)(acc[mt][u][q] + bv[mt][q]);
                    *(f16x4*)&w64_s[(16 * u + lr) * 64 + 16 * mt + 4 * g] = wv;
                }
        }
    }
    BAR();                                   // B5: hid dots + w64 done

    // ---- hid registers with fused inp_b add + ReLU
    f16x4 hidr[4][2];                        // [mt][u]
    #pragma unroll
    for (int mt = 0; mt < 4; ++mt)
        #pragma unroll
        for (int u = 0; u < 2; ++u) {
            const int s = 16 * u + lr;
            f16x4 xh;
            #pragma unroll
            for (int q = 0; q < 4; ++q) {
                const int h = 16 * mt + 4 * g + q;
                xh[q] = (f16)fmaxf(hid_s[s * 68 + h] + (float)w64_s[s * 64 + h], 0.f);
            }
            hidr[mt][u] = xh;
        }

    // ---- out chunks 65..74: wave w -> 65+w; waves 0,1 also 73,74
    auto do_out = [&](int c) {
        f32x4 bv[4];
        #pragma unroll
        for (int mt = 0; mt < 4; ++mt)
            bv[mt] = *(const f32x4*)&b4[64 * c + 16 * mt + 4 * g];
        f32x4 acc[4][2];
        #pragma unroll
        for (int mt = 0; mt < 4; ++mt)
            #pragma unroll
            for (int u = 0; u < 2; ++u) acc[mt][u] = zero;
        #pragma unroll
        for (int kk = 0; kk < 4; ++kk) {
            f16x8 af[4];
            LDAF(af, c, kk)
            MFMA8(af, kk)
        }
        #pragma unroll
        for (int u = 0; u < 2; ++u) {
            float sum = 0.f;
            #pragma unroll
            for (int mt = 0; mt < 4; ++mt)
                #pragma unroll
                for (int q = 0; q < 4; ++q)
                    sum += (acc[mt][u][q] + bv[mt][q]) * (float)hidr[mt][u][q];
            sum += __shfl_xor(sum, 16);
            sum += __shfl_xor(sum, 32);
            if (g == 0) res_s[(16 * u + lr) * 12 + (c - 65)] = sum;
        }
    };
    do_out(65 + w);
    if (w < 2) do_out(73 + w);

    // ---- chunk 75 (out_b rows 4800..4809): wave 2 -> res_b
    if (w == 2) {
        f32x4 accb[2] = {zero, zero};
        #pragma unroll
        for (int kk = 0; kk < 4; ++kk) {
            const f16x8 af = *(const f16x8*)(W4b + (size_t)75 * 16384 + kk * 4096 + afoff);
            #pragma unroll
            for (int u = 0; u < 2; ++u)
                accb[u] = __builtin_amdgcn_mfma_f32_16x16x32_f16(af, bfrag[kk][u], accb[u], 0, 0, 0);
        }
        #pragma unroll
        for (int u = 0; u < 2; ++u)
            #pragma unroll
            for (int q = 0; q < 4; ++q) {
                const int o = 4 * g + q;
                if (o < 10)
                    res_b[(16 * u + lr) * 12 + o] = accb[u][q] + b4[4800 + o];
            }
    }
    BAR();                                   // B6: res ready

    for (int e = t; e < 320; e += 512)
        out[(size_t)row0 * 10 + e] =
            res_s[(e / 10) * 12 + (e % 10)] + res_b[(e / 10) * 12 + (e % 10)];
#undef LDAF
#undef MFMA8
}

// ---------------------------------------------------------------- launcher
extern "C" void kernel_launch(void* const* d_in, const int* in_sizes, int n_in,
                              void* d_out, int out_size, void* d_ws, size_t ws_size,
                              hipStream_t stream)
{
    const float* data = (const float*)d_in[0];
    const int*   midx = (const int*)d_in[1];
    const float* W1   = (const float*)d_in[2];
    const float* b1   = (const float*)d_in[3];
    const float* W2   = (const float*)d_in[4];
    const float* b2   = (const float*)d_in[5];
    const float* W3   = (const float*)d_in[6];
    const float* b3   = (const float*)d_in[7];
    const float* W4   = (const float*)d_in[8];
    const float* b4   = (const float*)d_in[9];
    float* out = (float*)d_out;

    f16* W1Th = (f16*)d_ws;                    // 262144 f16
    f16* W4s  = W1Th + (size_t)4096 * 64;      // 622592 f16 (fragment-ordered)
    f16* W2h  = W4s + (size_t)NPAD * 128;      // 16384 f16
    f16* W3h  = W2h + 256 * 64;                // 32768 f16

    k_prep<<<512, 256, 0, stream>>>(W1, W2, W3, W4, W1Th, W2h, W3h, W4s);
    k_main<<<512, 512, 0, stream>>>(data, midx, W1Th, b1, W2h, b2, W3h, b3,
                                    W4s, b4, out);
}

// Round 17
// 75.058 us; speedup vs baseline: 1.4408x; 1.0111x over previous
//
#include <hip/hip_runtime.h>

// INP=4096 MSK=64 HID=64 OUT=10  L1=64 L2=256 L3=128  B=16384  WVEC=4810
// BEST-KNOWN CONFIG (r11, 74.7us): k_prep + wave-specialized k_main.
// k_prep : W1^T -> f16; W2/W3 -> f16; W4 -> f16 in MFMA fragment order
// k_main : grid 256 x 512 thr. WAVE-SPECIALIZED:
//   wave 7  = gather producer: issues all 64 xm random-load instrs at t~0,
//             parks at RAW barriers (no vmcnt drain), drains + writes xm_s
//             just before the xm-barrier, then joins the GEMM.
//   waves 0-6 = front: L1 dedup-sum, L2/L3 f16 MFMA under the gather.
//   then all 8 waves: register-resident W4 GEMM (fragment-ordered A stream
//   from L2, 4 MFMA per A-load) + fused per-sample einsum epilogues.
// Structural wall (measured r12-r16): per-CU miss-queue on the mandatory
// 59MB random gather (~40us) + serial post-xm GEMM (~15us) + prep/launch
// (~14us) => ~70us floor; this config sits within ~5% of it.

typedef _Float16 f16;
typedef _Float16 f16x8 __attribute__((ext_vector_type(8)));
typedef _Float16 f16x4 __attribute__((ext_vector_type(4)));
typedef float    f32x4 __attribute__((ext_vector_type(4)));

#define NPAD 4864   // 4810 W4 rows padded to 76*64

#define BAR() do { asm volatile("s_waitcnt lgkmcnt(0)" ::: "memory"); \
                   __builtin_amdgcn_s_barrier();                      \
                   asm volatile("" ::: "memory"); } while (0)

// ---------------------------------------------------------------- prep
__global__ __launch_bounds__(256) void k_prep(
    const float* __restrict__ W1, const float* __restrict__ W2,
    const float* __restrict__ W3, const float* __restrict__ W4,
    f16* __restrict__ W1Th, f16* __restrict__ W2h,
    f16* __restrict__ W3h, f16* __restrict__ W4s)
{
    const int tid = blockIdx.x * 256 + threadIdx.x;
    const int stride = gridDim.x * 256;
    for (int e = tid; e < 4096 * 64; e += stride) {
        int j = e >> 6, i = e & 63;
        W1Th[e] = (f16)W1[(size_t)i * 4096 + j];
    }
    for (int e = tid; e < NPAD * 128; e += stride) {
        const int j    = e & 7;
        const int lane = (e >> 3) & 63;
        const int mt   = (e >> 9) & 3;
        const int kk   = (e >> 11) & 3;
        const int c    = e >> 13;
        const int lr = lane & 15, g = lane >> 4;
        const int row = 64 * c + 16 * mt + lr;
        const int col = 32 * kk + 8 * g + j;
        W4s[e] = (row < 4810) ? (f16)W4[(size_t)row * 128 + col] : (f16)0.f;
    }
    for (int e = tid; e < 256 * 64; e += stride)  W2h[e] = (f16)W2[e];
    for (int e = tid; e < 128 * 256; e += stride) W3h[e] = (f16)W3[e];
}

// ---------------------------------------------------------------- main
__global__ __launch_bounds__(512, 2) void k_main(
    const float* __restrict__ data, const int* __restrict__ midx,
    const f16* __restrict__ W1Th, const float* __restrict__ b1,
    const f16* __restrict__ W2h, const float* __restrict__ b2,
    const f16* __restrict__ W3h, const float* __restrict__ b3,
    const f16* __restrict__ W4s, const float* __restrict__ b4,
    float* __restrict__ out)
{
    __shared__ __align__(16) int   idx_s[64 * 64];    // 16 KB
    __shared__ __align__(16) char  h1b[8192];         // h1 f16 swz
    __shared__ __align__(16) char  h2b[32768];        // h2 f16 swz
    __shared__ __align__(16) char  h3b[16384];        // h3 f16 swz
    __shared__ __align__(16) float xm_s[64 * 68];     // 17.4 KB
    __shared__ __align__(16) float hid_s[64 * 68];    // 17.4 KB
    __shared__ __align__(16) f16   w64_s[64 * 64];    // 8 KB (inp_b tile)
    __shared__ __align__(16) float res_s[64 * 12];    // 3 KB
    __shared__ __align__(16) float res_b[64 * 12];    // 3 KB (out_b tile)

    const int t = threadIdx.x, w = t >> 6, lane = t & 63;
    const int lr = lane & 15, g = lane >> 4;
    const int row0 = blockIdx.x * 64;
    const f32x4 zero = {0.f, 0.f, 0.f, 0.f};

    // ---- stage idx (all waves; wave 7's loads retire before its gathers)
    for (int e = t; e < 4096; e += 512)
        idx_s[e] = midx[(size_t)row0 * 64 + e];
    BAR();                                   // B0: idx ready

    float xr[64];                            // live only on wave-7 path

    if (w == 7) {
        // ---- issue ALL 64 gather instrs; keep them outstanding across
        // the raw barriers (no other vector loads in this wave's stream).
        #pragma unroll
        for (int k = 0; k < 64; ++k)
            xr[k] = data[(size_t)(row0 + k) * 4096 + idx_s[k * 64 + lane]];
        __builtin_amdgcn_sched_barrier(0);
    } else {
        // ---- L1 dedup gather-sum: sample-pairs sp = w, w+7, ... (<32)
        const f32x4 b1v = *(const f32x4*)&b1[lr * 4];
        for (int sp = w; sp < 32; sp += 7) {
            const int s0 = 2 * sp, s1 = s0 + 1;
            f32x4 a0 = zero, a1 = zero;
            #pragma unroll
            for (int tt = 0; tt < 16; ++tt) {
                const int i = g * 16 + tt;
                const int c0 = idx_s[s0 * 64 + i];
                const int q0 = (i > 0) ? idx_s[s0 * 64 + i - 1] : -1;
                const int c1 = idx_s[s1 * 64 + i];
                const int q1 = (i > 0) ? idx_s[s1 * 64 + i - 1] : -1;
                const f16x4 w0 = *(const f16x4*)&W1Th[c0 * 64 + lr * 4];
                const f16x4 w1 = *(const f16x4*)&W1Th[c1 * 64 + lr * 4];
                #pragma unroll
                for (int q = 0; q < 4; ++q) {
                    a0[q] += (c0 != q0) ? (float)w0[q] : 0.f;
                    a1[q] += (c1 != q1) ? (float)w1[q] : 0.f;
                }
            }
            #pragma unroll
            for (int q = 0; q < 4; ++q) {
                a0[q] += __shfl_xor(a0[q], 16);
                a0[q] += __shfl_xor(a0[q], 32);
                a1[q] += __shfl_xor(a1[q], 16);
                a1[q] += __shfl_xor(a1[q], 32);
            }
            if (g == 0) {
                f16x4 h0, h1v;
                #pragma unroll
                for (int q = 0; q < 4; ++q) {
                    h0[q]  = (f16)fmaxf(a0[q] + b1v[q], 0.f);
                    h1v[q] = (f16)fmaxf(a1[q] + b1v[q], 0.f);
                }
                *(f16x4*)(h1b + ((s0 * 128 + lr * 8) ^ ((s0 & 7) << 4))) = h0;
                *(f16x4*)(h1b + ((s1 * 128 + lr * 8) ^ ((s1 & 7) << 4))) = h1v;
            }
        }
    }
    BAR();                                   // B1: h1 ready

    if (w < 7) {
        // ---- L2: n-blocks of 32, nb = w, w+7
        f16x8 bh[4][2];
        #pragma unroll
        for (int rt = 0; rt < 4; ++rt)
            #pragma unroll
            for (int kk = 0; kk < 2; ++kk) {
                const int s = 16 * rt + lr;
                bh[rt][kk] = *(const f16x8*)(h1b + ((s * 128 + (32 * kk + 8 * g) * 2) ^ ((s & 7) << 4)));
            }
        for (int nb = w; nb < 8; nb += 7) {
            const int n0 = 32 * nb;
            f16x8 a2[2][2];
            #pragma unroll
            for (int mt = 0; mt < 2; ++mt)
                #pragma unroll
                for (int kk = 0; kk < 2; ++kk)
                    a2[mt][kk] = *(const f16x8*)&W2h[(n0 + 16 * mt + lr) * 64 + 32 * kk + 8 * g];
            f32x4 acc2[2][4];
            #pragma unroll
            for (int mt = 0; mt < 2; ++mt)
                #pragma unroll
                for (int rt = 0; rt < 4; ++rt) {
                    acc2[mt][rt] = __builtin_amdgcn_mfma_f32_16x16x32_f16(a2[mt][0], bh[rt][0], zero, 0, 0, 0);
                    acc2[mt][rt] = __builtin_amdgcn_mfma_f32_16x16x32_f16(a2[mt][1], bh[rt][1], acc2[mt][rt], 0, 0, 0);
                }
            #pragma unroll
            for (int mt = 0; mt < 2; ++mt) {
                const f32x4 bv = *(const f32x4*)&b2[n0 + 16 * mt + 4 * g];
                #pragma unroll
                for (int rt = 0; rt < 4; ++rt) {
                    const int s = 16 * rt + lr;
                    f16x4 hv;
                    #pragma unroll
                    for (int q = 0; q < 4; ++q)
                        hv[q] = (f16)fmaxf(acc2[mt][rt][q] + bv[q], 0.f);
                    *(f16x4*)(h2b + ((s * 512 + (n0 + 16 * mt + 4 * g) * 2) ^ ((s & 7) << 4))) = hv;
                }
            }
        }
    }
    BAR();                                   // B2: h2 ready

    if (w < 7) {
        // ---- L3: n-blocks of 16, nb = w, w+7
        for (int nb = w; nb < 8; nb += 7) {
            const int n0 = 16 * nb;
            f32x4 acc3[4] = {zero, zero, zero, zero};
            #pragma unroll 2
            for (int kk = 0; kk < 8; ++kk) {
                const f16x8 a3 = *(const f16x8*)&W3h[(n0 + lr) * 256 + 32 * kk + 8 * g];
                #pragma unroll
                for (int rt = 0; rt < 4; ++rt) {
                    const int s = 16 * rt + lr;
                    const f16x8 bb = *(const f16x8*)(h2b + ((s * 512 + (32 * kk + 8 * g) * 2) ^ ((s & 7) << 4)));
                    acc3[rt] = __builtin_amdgcn_mfma_f32_16x16x32_f16(a3, bb, acc3[rt], 0, 0, 0);
                }
            }
            const f32x4 bv3 = *(const f32x4*)&b3[n0 + 4 * g];
            #pragma unroll
            for (int rt = 0; rt < 4; ++rt) {
                const int s = 16 * rt + lr;
                f16x4 hv;
                #pragma unroll
                for (int q = 0; q < 4; ++q)
                    hv[q] = (f16)fmaxf(acc3[rt][q] + bv3[q], 0.f);
                *(f16x4*)(h3b + ((s * 256 + (n0 + 4 * g) * 2) ^ ((s & 7) << 4))) = hv;
            }
        }
    }
    BAR();                                   // B3: h3 ready

    // ---- all waves: B-fragments for all 64 samples
    f16x8 bfrag[4][4];                       // [kk][u]
    #pragma unroll
    for (int u = 0; u < 4; ++u)
        #pragma unroll
        for (int kk = 0; kk < 4; ++kk) {
            const int s = 16 * u + lr;
            bfrag[kk][u] = *(const f16x8*)(h3b + ((s * 256 + (32 * kk + 8 * g) * 2) ^ ((s & 7) << 4)));
        }
    if (w == 7) {
        // drain gathers (compiler inserts minimal in-order vmcnt) -> xm_s
        #pragma unroll
        for (int k = 0; k < 64; ++k)
            xm_s[k * 68 + lane] = xr[k];
    }
    BAR();                                   // B4: xm ready

    // xm packed f16 registers
    f16x4 xmr[4][4];                         // [mt][u]
    #pragma unroll
    for (int mt = 0; mt < 4; ++mt)
        #pragma unroll
        for (int u = 0; u < 4; ++u) {
            const f32x4 xv = *(const f32x4*)&xm_s[(16 * u + lr) * 68 + 16 * mt + 4 * g];
            f16x4 xh;
            #pragma unroll
            for (int q = 0; q < 4; ++q) xh[q] = (f16)xv[q];
            xmr[mt][u] = xh;
        }

    const char* W4b = (const char*)W4s;
    const int afoff = lane * 16;

#define LDAF(dst, c, kk) { const char* cb_ = W4b + (size_t)(c) * 16384 + (kk) * 4096 + afoff; \
    dst[0] = *(const f16x8*)(cb_);        dst[1] = *(const f16x8*)(cb_ + 1024); \
    dst[2] = *(const f16x8*)(cb_ + 2048); dst[3] = *(const f16x8*)(cb_ + 3072); }

#define MFMA16(af, kk) { \
    _Pragma("unroll") for (int mt = 0; mt < 4; ++mt) \
    _Pragma("unroll") for (int u = 0; u < 4; ++u) \
        acc[mt][u] = __builtin_amdgcn_mfma_f32_16x16x32_f16(af[mt], bfrag[kk][u], acc[mt][u], 0, 0, 0); }

    // ---- inp chunks 0..64 (8 waves): c = w, w+8, ...
    for (int c = w; c < 65; c += 8) {
        f16x8 afA[4], afB[4];
        LDAF(afA, c, 0)
        LDAF(afB, c, 1)
        f32x4 acc[4][4];
        #pragma unroll
        for (int mt = 0; mt < 4; ++mt)
            #pragma unroll
            for (int u = 0; u < 4; ++u)
                acc[mt][u] = __builtin_amdgcn_mfma_f32_16x16x32_f16(afA[mt], bfrag[0][u], zero, 0, 0, 0);
        LDAF(afA, c, 2)
        MFMA16(afB, 1)
        LDAF(afB, c, 3)
        MFMA16(afA, 2)
        MFMA16(afB, 3)

        f32x4 bv[4];
        #pragma unroll
        for (int mt = 0; mt < 4; ++mt)
            bv[mt] = *(const f32x4*)&b4[64 * c + 16 * mt + 4 * g];

        if (c < 64) {                        // inp_w: dot with xm -> hid_s
            #pragma unroll
            for (int u = 0; u < 4; ++u) {
                float sum = 0.f;
                #pragma unroll
                for (int mt = 0; mt < 4; ++mt)
                    #pragma unroll
                    for (int q = 0; q < 4; ++q)
                        sum += (acc[mt][u][q] + bv[mt][q]) * (float)xmr[mt][u][q];
                sum += __shfl_xor(sum, 16);
                sum += __shfl_xor(sum, 32);
                if (g == 0) hid_s[(16 * u + lr) * 68 + c] = sum;
            }
        } else {                             // inp_b tile -> w64_s (f16)
            #pragma unroll
            for (int u = 0; u < 4; ++u)
                #pragma unroll
                for (int mt = 0; mt < 4; ++mt) {
                    f16x4 wv;
                    #pragma unroll
                    for (int q = 0; q < 4; ++q)
                        wv[q] = (f16)(acc[mt][u][q] + bv[mt][q]);
                    *(f16x4*)&w64_s[(16 * u + lr) * 64 + 16 * mt + 4 * g] = wv;
                }
        }
    }
    BAR();                                   // B5: hid dots + w64 done

    // ---- hid registers with fused inp_b add + ReLU
    f16x4 hidr[4][4];                        // [mt][u]
    #pragma unroll
    for (int mt = 0; mt < 4; ++mt)
        #pragma unroll
        for (int u = 0; u < 4; ++u) {
            const int s = 16 * u + lr;
            f16x4 xh;
            #pragma unroll
            for (int q = 0; q < 4; ++q) {
                const int h = 16 * mt + 4 * g + q;
                xh[q] = (f16)fmaxf(hid_s[s * 68 + h] + (float)w64_s[s * 64 + h], 0.f);
            }
            hidr[mt][u] = xh;
        }

    // ---- out chunks 65..74: wave w -> 65+w; waves 0,1 also 73,74
    auto do_out = [&](int c) {
        f32x4 bv[4];
        #pragma unroll
        for (int mt = 0; mt < 4; ++mt)
            bv[mt] = *(const f32x4*)&b4[64 * c + 16 * mt + 4 * g];
        f16x8 afA[4], afB[4];
        LDAF(afA, c, 0)
        LDAF(afB, c, 1)
        f32x4 acc[4][4];
        #pragma unroll
        for (int mt = 0; mt < 4; ++mt)
            #pragma unroll
            for (int u = 0; u < 4; ++u)
                acc[mt][u] = __builtin_amdgcn_mfma_f32_16x16x32_f16(afA[mt], bfrag[0][u], zero, 0, 0, 0);
        LDAF(afA, c, 2)
        MFMA16(afB, 1)
        LDAF(afB, c, 3)
        MFMA16(afA, 2)
        MFMA16(afB, 3)
        #pragma unroll
        for (int u = 0; u < 4; ++u) {
            float sum = 0.f;
            #pragma unroll
            for (int mt = 0; mt < 4; ++mt)
                #pragma unroll
                for (int q = 0; q < 4; ++q)
                    sum += (acc[mt][u][q] + bv[mt][q]) * (float)hidr[mt][u][q];
            sum += __shfl_xor(sum, 16);
            sum += __shfl_xor(sum, 32);
            if (g == 0) res_s[(16 * u + lr) * 12 + (c - 65)] = sum;
        }
    };
    do_out(65 + w);
    if (w < 2) do_out(73 + w);

    // ---- chunk 75 (out_b rows 4800..4809): wave 2 -> res_b
    if (w == 2) {
        f32x4 accb[4] = {zero, zero, zero, zero};
        #pragma unroll
        for (int kk = 0; kk < 4; ++kk) {
            const f16x8 af = *(const f16x8*)(W4b + (size_t)75 * 16384 + kk * 4096 + afoff);
            #pragma unroll
            for (int u = 0; u < 4; ++u)
                accb[u] = __builtin_amdgcn_mfma_f32_16x16x32_f16(af, bfrag[kk][u], accb[u], 0, 0, 0);
        }
        #pragma unroll
        for (int u = 0; u < 4; ++u)
            #pragma unroll
            for (int q = 0; q < 4; ++q) {
                const int o = 4 * g + q;
                if (o < 10)
                    res_b[(16 * u + lr) * 12 + o] = accb[u][q] + b4[4800 + o];
            }
    }
    BAR();                                   // B6: res ready

    for (int e = t; e < 640; e += 512)
        out[(size_t)row0 * 10 + e] =
            res_s[(e / 10) * 12 + (e % 10)] + res_b[(e / 10) * 12 + (e % 10)];
#undef LDAF
#undef MFMA16
}

// ---------------------------------------------------------------- launcher
extern "C" void kernel_launch(void* const* d_in, const int* in_sizes, int n_in,
                              void* d_out, int out_size, void* d_ws, size_t ws_size,
                              hipStream_t stream)
{
    const float* data = (const float*)d_in[0];
    const int*   midx = (const int*)d_in[1];
    const float* W1   = (const float*)d_in[2];
    const float* b1   = (const float*)d_in[3];
    const float* W2   = (const float*)d_in[4];
    const float* b2   = (const float*)d_in[5];
    const float* W3   = (const float*)d_in[6];
    const float* b3   = (const float*)d_in[7];
    const float* W4   = (const float*)d_in[8];
    const float* b4   = (const float*)d_in[9];
    float* out = (float*)d_out;

    f16* W1Th = (f16*)d_ws;                    // 262144 f16
    f16* W4s  = W1Th + (size_t)4096 * 64;      // 622592 f16 (fragment-ordered)
    f16* W2h  = W4s + (size_t)NPAD * 128;      // 16384 f16
    f16* W3h  = W2h + 256 * 64;                // 32768 f16

    k_prep<<<512, 256, 0, stream>>>(W1, W2, W3, W4, W1Th, W2h, W3h, W4s);
    k_main<<<256, 512, 0, stream>>>(data, midx, W1Th, b1, W2h, b2, W3h, b3,
                                    W4s, b4, out);
}